// Round 2
// baseline (178.487 us; speedup 1.0000x reference)
//
#include <hip/hip_runtime.h>
#include <hip/hip_fp16.h>

// GCNRegressor: x[n,128] --GCNConv(W1)--> relu --GCNConv(W2)--> relu --@Wl+bl--> out[n]
// n=100000, E=1600000, IN=128, HID=64.
// R1: CSR-by-dst + gather aggregation (killed 102M fp32 atomics): 2913 -> 792 us.
// R2: 3-phase hierarchical scan + x4-unrolled gather: 792 -> 423 us.
// R3: two-level counting sort for CSR build (killed k_fill's 16x write amp): 423 -> 320.
// R4: fp16 scaled features (hs = h*dinv) halved the gather compulsory-fetch: 320 -> 302.
// R5: k_bin occupancy fix (BIN_CH 16384->2048) + deeper unroll: 302 -> 282.
// R6: 4-rows-per-VMEM gather (wave = 4 groups x 16 lanes): 282 -> 243.
// R7: register-tiled 4x4 fp32 GEMM (LDS-issue fix): 243 -> 225.
// R8: MFMA fp16 GEMMs + fp16 relu output + gather unroll 4: 225 -> 191.
// R9: fixed-capacity buckets (WIN) + gather unroll 8 (REGRESSION, VALU): 191 -> 178.
// R10: byte-offset colidx + packed rowptr (beg<<8|deg): 178 -> 171.
// R11: 8-rows-per-VMEM gather (wave = 8 groups x 8 lanes, uint4/lane): 2x rows
//      in flight, half the per-edge addressing VALU (R9's goal w/o its cost).
// R12: v_dot2_f32_f16 accumulate + 2-slot loop: VALUBusy 72->57 but REGRESSED
//      (43.1us) -- 2-slot iterations serialize the colidx->gather latency chain;
//      43% of nodes (deg 17..32) went 1 -> 2 round-trips.
// R13: straight-line first 4 slots (single latency round-trip for deg<=32,
//      ~all nodes) with ALL loads issued up-front (dummy-masked, broadcast) and
//      dot2s skipped per-slot behind wave-uniform branches. Rare tail loop for
//      deg>32. = R11's latency profile + R12's VALU profile.

#define SHIFT 9
#define BSZ   (1 << SHIFT)     // 512 nodes per bucket
#define NBMAX 256
#define BIN_CH 2048
#define BCAP  12288            // per-bucket capacity (mean 8188, 1.5x slack)

using f16x8 = __attribute__((ext_vector_type(8))) _Float16;
using f16x2 = __attribute__((ext_vector_type(2))) _Float16;
using f32x4 = __attribute__((ext_vector_type(4))) float;

// ---- Phase 1: bin edges into fixed-capacity buckets; bcursor = counts ----
// pack src(17b) | local_node(9b)<<17. Block 0 also zeroes the dummy hs row.
__global__ __launch_bounds__(256) void k_bin(const int* __restrict__ src,
                                             const int* __restrict__ dst,
                                             int* __restrict__ bcursor,
                                             unsigned* __restrict__ binned,
                                             __half* __restrict__ hs, int n, int E) {
    if (blockIdx.x == 0 && threadIdx.x < 8) {
        uint4 z = {0u, 0u, 0u, 0u};
        reinterpret_cast<uint4*>(hs + ((size_t)n << 6))[threadIdx.x] = z;
    }
    __shared__ int h[NBMAX];
    __shared__ int base[NBMAX];
    const int beg = blockIdx.x * BIN_CH;
    const int end = min(beg + BIN_CH, E);
    for (int i = threadIdx.x; i < NBMAX; i += 256) h[i] = 0;
    __syncthreads();
    for (int e = beg + threadIdx.x; e < end; e += 256)
        atomicAdd(&h[dst[e] >> SHIFT], 1);
    __syncthreads();
    for (int i = threadIdx.x; i < NBMAX; i += 256) {
        base[i] = h[i] ? atomicAdd(&bcursor[i], h[i]) : 0;
        h[i] = 0;  // reuse as local cursor
    }
    __syncthreads();
    for (int e = beg + threadIdx.x; e < end; e += 256) {
        int d = dst[e];
        int b = d >> SHIFT;
        int off = atomicAdd(&h[b], 1);
        binned[(size_t)b * BCAP + base[b] + off] =
            (unsigned)src[e] | ((unsigned)(d & (BSZ - 1)) << 17);
    }
}

// ---- Phase 2: per-bucket prefix + LDS count + scan + packed rowptr + place ----
// rowptr[g] = (edge_base << 8) | deg ; colidx entry = src_row_byte_offset (src<<7)
__global__ __launch_bounds__(256) void k_bfill(const unsigned* __restrict__ binned,
                                               const int* __restrict__ counts,
                                               int* __restrict__ rowptr,
                                               int* __restrict__ colidx,
                                               float* __restrict__ dinv, int n) {
    __shared__ int cnt[BSZ];
    __shared__ int nbase[BSZ];
    __shared__ int stmp[256];
    const int b = blockIdx.x;
    const int t = threadIdx.x;
    // prefix sum of counts[0..b) -> ebeg (nb <= 256, single stride)
    stmp[t] = (t < b) ? counts[t] : 0;
    __syncthreads();
    for (int off = 128; off; off >>= 1) {
        if (t < off) stmp[t] += stmp[t + off];
        __syncthreads();
    }
    const int ebeg = stmp[0];
    const int ecnt = counts[b];
    __syncthreads();
    const unsigned* bp = binned + (size_t)b * BCAP;
    for (int i = t; i < BSZ; i += 256) cnt[i] = 0;
    __syncthreads();
    for (int e = t; e < ecnt; e += 256)
        atomicAdd(&cnt[bp[e] >> 17], 1);
    __syncthreads();
    int c0 = cnt[2 * t], c1 = cnt[2 * t + 1];
    int s = c0 + c1;
    stmp[t] = s;
    __syncthreads();
    for (int off = 1; off < 256; off <<= 1) {
        int u = (t >= off) ? stmp[t - off] : 0;
        __syncthreads();
        stmp[t] += u;
        __syncthreads();
    }
    int ex = stmp[t] - s;
    nbase[2 * t] = ex;
    nbase[2 * t + 1] = ex + c0;
    __syncthreads();
    const int gbase = b << SHIFT;
    for (int j = t; j < BSZ; j += 256) {
        int g = gbase + j;
        if (g < n) {
            rowptr[g] = (int)(((unsigned)(ebeg + nbase[j]) << 8) |
                              (unsigned)min(cnt[j], 255));
            dinv[g] = rsqrtf((float)cnt[j] + 1.0f);
        }
        cnt[j] = nbase[j];  // becomes local cursor
    }
    __syncthreads();
    for (int e = t; e < ecnt; e += 256) {
        unsigned p = bp[e];
        int j = p >> 17;
        int off = atomicAdd(&cnt[j], 1);
        colidx[ebeg + off] = (int)((p & 0x1FFFFu) << 7);  // byte offset of src row
    }
}

// MFMA GEMM: C16[n,64] = fp16( (A[n,K] @ W[K,64]) * dinv[row] ).
// Block = 256 threads = 4 waves; wave w computes rows rb+w*16..+15, all 64 cols.
template <int K, bool A_FP32>
__global__ __launch_bounds__(256) void k_gemm_mfma(const void* __restrict__ Av,
                                                   const float* __restrict__ W,
                                                   const float* __restrict__ dinv,
                                                   __half* __restrict__ C, int n) {
    constexpr int KP = K + 8;  // padded LDS row stride in halves (16B aligned)
    __shared__ _Float16 Wt[64 * KP];
    const int tid = threadIdx.x;
    for (int i = tid; i < K * 64; i += 256) {
        int k = i >> 6, c = i & 63;
        Wt[c * KP + k] = (_Float16)W[i];
    }
    __syncthreads();

    const int lane = tid & 63;
    const int wv = tid >> 6;
    const int r16 = lane & 15;
    const int kq = lane >> 4;                       // 0..3
    const int rb = blockIdx.x * 64 + wv * 16;
    const int arow = min(rb + r16, n - 1);          // clamped A row for this lane

    f32x4 acc[4] = {{0.f,0.f,0.f,0.f},{0.f,0.f,0.f,0.f},
                    {0.f,0.f,0.f,0.f},{0.f,0.f,0.f,0.f}};

#pragma unroll
    for (int kk = 0; kk < K; kk += 32) {
        f16x8 a;
        if (A_FP32) {
            const float* Ap = (const float*)Av + (size_t)arow * K + kk + kq * 8;
            float4 f0 = *reinterpret_cast<const float4*>(Ap);
            float4 f1 = *reinterpret_cast<const float4*>(Ap + 4);
            a[0] = (_Float16)f0.x; a[1] = (_Float16)f0.y;
            a[2] = (_Float16)f0.z; a[3] = (_Float16)f0.w;
            a[4] = (_Float16)f1.x; a[5] = (_Float16)f1.y;
            a[6] = (_Float16)f1.z; a[7] = (_Float16)f1.w;
        } else {
            const _Float16* Ap = (const _Float16*)Av + (size_t)arow * K + kk + kq * 8;
            a = *reinterpret_cast<const f16x8*>(Ap);
        }
#pragma unroll
        for (int nt = 0; nt < 4; ++nt) {
            f16x8 b = *reinterpret_cast<const f16x8*>(&Wt[(nt * 16 + r16) * KP + kk + kq * 8]);
            acc[nt] = __builtin_amdgcn_mfma_f32_16x16x32_f16(a, b, acc[nt], 0, 0, 0);
        }
    }

#pragma unroll
    for (int r = 0; r < 4; ++r) {
        const int row = rb + kq * 4 + r;
        if (row < n) {
            const float di = dinv[row];
#pragma unroll
            for (int nt = 0; nt < 4; ++nt)
                C[((size_t)row << 6) + nt * 16 + r16] = __float2half(acc[nt][r] * di);
        }
    }
}

// Accumulate 8 fp16 (one uint4) into acc[8] via v_dot2_f32_f16: one VALU op per
// value (convert+add fused, fp32 accumulate). Masks (1,0)/(0,1) keep channels
// separate; exact 1.0-multiply => bit-identical to cvt+add.
__device__ __forceinline__ void dotu4(float acc[8], uint4 u, f16x2 pl, f16x2 ph) {
    union { uint4 u4; f16x2 h[4]; } v;
    v.u4 = u;
    acc[0] = __builtin_amdgcn_fdot2(v.h[0], pl, acc[0], false);
    acc[1] = __builtin_amdgcn_fdot2(v.h[0], ph, acc[1], false);
    acc[2] = __builtin_amdgcn_fdot2(v.h[1], pl, acc[2], false);
    acc[3] = __builtin_amdgcn_fdot2(v.h[1], ph, acc[3], false);
    acc[4] = __builtin_amdgcn_fdot2(v.h[2], pl, acc[4], false);
    acc[5] = __builtin_amdgcn_fdot2(v.h[2], ph, acc[5], false);
    acc[6] = __builtin_amdgcn_fdot2(v.h[3], pl, acc[6], false);
    acc[7] = __builtin_amdgcn_fdot2(v.h[3], ph, acc[7], false);
}

// Gather core: wave = 8 edge-groups x 8 lanes; uint4 (16B) per lane -> one VMEM
// fetches 8 full rows. First 4 slots (deg <= 32, ~all nodes) are straight-line:
// ALL loads issued up-front (dummy-masked loads broadcast to the hot zero row,
// ~free), dot2s executed per-slot behind WAVE-UNIFORM branches (deg is uniform
// across the wave). One latency round-trip + no dummy-slot VALU. Rare tail loop
// (deg > 32) keeps the unconditional masked 4-slot body. colidx holds BYTE
// offsets. After fold, ALL lanes hold the full 8-channel sums for their p.
__device__ __forceinline__ void gather_sum8(const char* __restrict__ hsb,
                                            const int* __restrict__ colidx,
                                            unsigned pk, int g, int p,
                                            unsigned dum, float acc[8]) {
    const f16x2 pl = {(_Float16)1.0f, (_Float16)0.0f};
    const f16x2 ph = {(_Float16)0.0f, (_Float16)1.0f};
    const int beg = (int)(pk >> 8);
    const int deg = (int)(pk & 255u);
    const int t = deg - g;                 // slot k valid iff 8*k < t
    const unsigned poff = (unsigned)(p << 4);
    const unsigned dumo = dum + poff;
    const int nslot = (deg + 7) >> 3;      // wave-uniform
    {
        const int ib = beg + g;
        unsigned c0 = (unsigned)colidx[ib]      + poff;  // slack past E is safe
        unsigned c1 = (unsigned)colidx[ib + 8]  + poff;
        unsigned c2 = (unsigned)colidx[ib + 16] + poff;
        unsigned c3 = (unsigned)colidx[ib + 24] + poff;
        unsigned o0 = (0  < t) ? c0 : dumo;
        unsigned o1 = (8  < t) ? c1 : dumo;
        unsigned o2 = (16 < t) ? c2 : dumo;
        unsigned o3 = (24 < t) ? c3 : dumo;
        uint4 u0 = *reinterpret_cast<const uint4*>(hsb + o0);
        uint4 u1 = *reinterpret_cast<const uint4*>(hsb + o1);
        uint4 u2 = *reinterpret_cast<const uint4*>(hsb + o2);
        uint4 u3 = *reinterpret_cast<const uint4*>(hsb + o3);
        dotu4(acc, u0, pl, ph);
        if (nslot > 1) {
            dotu4(acc, u1, pl, ph);
            if (nslot > 2) {
                dotu4(acc, u2, pl, ph);
                if (nslot > 3) dotu4(acc, u3, pl, ph);
            }
        }
    }
    for (int k = 4; k < nslot; k += 4) {   // rare: deg > 32
        const int ib = beg + 8 * k + g;
        unsigned c0 = (unsigned)colidx[ib]      + poff;
        unsigned c1 = (unsigned)colidx[ib + 8]  + poff;
        unsigned c2 = (unsigned)colidx[ib + 16] + poff;
        unsigned c3 = (unsigned)colidx[ib + 24] + poff;
        const int kb = 8 * k;
        unsigned o0 = (kb      < t) ? c0 : dumo;
        unsigned o1 = (kb + 8  < t) ? c1 : dumo;
        unsigned o2 = (kb + 16 < t) ? c2 : dumo;
        unsigned o3 = (kb + 24 < t) ? c3 : dumo;
        uint4 u0 = *reinterpret_cast<const uint4*>(hsb + o0);
        uint4 u1 = *reinterpret_cast<const uint4*>(hsb + o1);
        uint4 u2 = *reinterpret_cast<const uint4*>(hsb + o2);
        uint4 u3 = *reinterpret_cast<const uint4*>(hsb + o3);
        dotu4(acc, u0, pl, ph);
        dotu4(acc, u1, pl, ph);
        dotu4(acc, u2, pl, ph);
        dotu4(acc, u3, pl, ph);
    }
#pragma unroll
    for (int m = 8; m <= 32; m <<= 1) {
#pragma unroll
        for (int j = 0; j < 8; ++j)
            acc[j] += __shfl_xor(acc[j], m, 64);
    }
}

// conv1 aggregation: out16 = fp16(relu(di*(sum_e hs[src_e] + hs_i) + b)).
__global__ __launch_bounds__(256) void k_agg_relu(const __half* __restrict__ hs,
                                                  const int* __restrict__ rowptr,
                                                  const int* __restrict__ colidx,
                                                  const float* __restrict__ dinv,
                                                  const float* __restrict__ b,
                                                  __half* __restrict__ out, int n) {
    const int i = blockIdx.x * 4 + (threadIdx.x >> 6);
    const int lane = threadIdx.x & 63;
    if (i >= n) return;
    const int g = lane >> 3, p = lane & 7;
    float acc[8] = {};
    gather_sum8((const char*)hs, colidx, (unsigned)rowptr[i], g, p,
                (unsigned)n << 7, acc);
    if (lane < 8) {
        const f16x2 pl = {(_Float16)1.0f, (_Float16)0.0f};
        const f16x2 ph = {(_Float16)0.0f, (_Float16)1.0f};
        uint4 su = *reinterpret_cast<const uint4*>(hs + ((size_t)i << 6) + (p << 3));
        dotu4(acc, su, pl, ph);
        const float di = dinv[i];
        float4 b0 = *reinterpret_cast<const float4*>(b + (p << 3));
        float4 b1 = *reinterpret_cast<const float4*>(b + (p << 3) + 4);
        __half2 h0 = __halves2half2(__float2half(fmaxf(fmaf(acc[0], di, b0.x), 0.f)),
                                    __float2half(fmaxf(fmaf(acc[1], di, b0.y), 0.f)));
        __half2 h1 = __halves2half2(__float2half(fmaxf(fmaf(acc[2], di, b0.z), 0.f)),
                                    __float2half(fmaxf(fmaf(acc[3], di, b0.w), 0.f)));
        __half2 h2 = __halves2half2(__float2half(fmaxf(fmaf(acc[4], di, b1.x), 0.f)),
                                    __float2half(fmaxf(fmaf(acc[5], di, b1.y), 0.f)));
        __half2 h3 = __halves2half2(__float2half(fmaxf(fmaf(acc[6], di, b1.z), 0.f)),
                                    __float2half(fmaxf(fmaf(acc[7], di, b1.w), 0.f)));
        uint4 u;
        u.x = *reinterpret_cast<unsigned*>(&h0);
        u.y = *reinterpret_cast<unsigned*>(&h1);
        u.z = *reinterpret_cast<unsigned*>(&h2);
        u.w = *reinterpret_cast<unsigned*>(&h3);
        *reinterpret_cast<uint4*>(out + ((size_t)i << 6) + (p << 3)) = u;
    }
}

// conv2 aggregation + relu + (.@Wl + bl) head, fused. One wave per node.
__global__ __launch_bounds__(256) void k_agg_head(const __half* __restrict__ hs,
                                                  const int* __restrict__ rowptr,
                                                  const int* __restrict__ colidx,
                                                  const float* __restrict__ dinv,
                                                  const float* __restrict__ b2,
                                                  const float* __restrict__ Wl,
                                                  const float* __restrict__ bl,
                                                  float* __restrict__ out, int n) {
    const int i = blockIdx.x * 4 + (threadIdx.x >> 6);
    const int lane = threadIdx.x & 63;
    if (i >= n) return;
    const int g = lane >> 3, p = lane & 7;
    float acc[8] = {};
    gather_sum8((const char*)hs, colidx, (unsigned)rowptr[i], g, p,
                (unsigned)n << 7, acc);
    // all lanes hold full sums; epilogue computed redundantly per group
    const f16x2 pl = {(_Float16)1.0f, (_Float16)0.0f};
    const f16x2 ph = {(_Float16)0.0f, (_Float16)1.0f};
    uint4 su = *reinterpret_cast<const uint4*>(hs + ((size_t)i << 6) + (p << 3));
    dotu4(acc, su, pl, ph);
    const float di = dinv[i];
    float4 b0 = *reinterpret_cast<const float4*>(b2 + (p << 3));
    float4 b1 = *reinterpret_cast<const float4*>(b2 + (p << 3) + 4);
    float4 w0 = *reinterpret_cast<const float4*>(Wl + (p << 3));
    float4 w1 = *reinterpret_cast<const float4*>(Wl + (p << 3) + 4);
    float v = fmaxf(fmaf(acc[0], di, b0.x), 0.f) * w0.x
            + fmaxf(fmaf(acc[1], di, b0.y), 0.f) * w0.y
            + fmaxf(fmaf(acc[2], di, b0.z), 0.f) * w0.z
            + fmaxf(fmaf(acc[3], di, b0.w), 0.f) * w0.w
            + fmaxf(fmaf(acc[4], di, b1.x), 0.f) * w1.x
            + fmaxf(fmaf(acc[5], di, b1.y), 0.f) * w1.y
            + fmaxf(fmaf(acc[6], di, b1.z), 0.f) * w1.z
            + fmaxf(fmaf(acc[7], di, b1.w), 0.f) * w1.w;
    v += __shfl_xor(v, 1, 64);
    v += __shfl_xor(v, 2, 64);
    v += __shfl_xor(v, 4, 64);
    if (lane == 0) out[i] = v + bl[0];
}

extern "C" void kernel_launch(void* const* d_in, const int* in_sizes, int n_in,
                              void* d_out, int out_size, void* d_ws, size_t ws_size,
                              hipStream_t stream) {
    const float* x  = (const float*)d_in[0];
    const int*   ei = (const int*)d_in[1];
    const float* W1 = (const float*)d_in[2];
    const float* b1 = (const float*)d_in[3];
    const float* W2 = (const float*)d_in[4];
    const float* b2 = (const float*)d_in[5];
    const float* Wl = (const float*)d_in[6];
    const float* bl = (const float*)d_in[7];
    float* out = (float*)d_out;

    const int n = in_sizes[0] / 128;   // 100000
    const int E = in_sizes[1] / 2;     // 1600000
    const int* src = ei;
    const int* dst = ei + E;
    const int nb = (n + BSZ - 1) >> SHIFT;  // 196

    char* ws = (char*)d_ws;
    size_t o = 0;
    auto alloc = [&](size_t bytes) {
        void* p = ws + o;
        o = (o + bytes + 255) & ~(size_t)255;
        return p;
    };
    float* dinv    = (float*)alloc((size_t)n * 4);
    int*   bcursor = (int*)  alloc((size_t)NBMAX * 4);
    int*   rowptr  = (int*)  alloc((size_t)(n + 1) * 4);
    int*   colidx  = (int*)  alloc(((size_t)E + 64) * 4);        // +slack for unrolled reads
    __half* hs     = (__half*)alloc((size_t)(n + 1) * 64 * 2);   // +1 zeroed dummy row
    __half* bufA   = (__half*)alloc((size_t)n * 64 * 2);         // fp16 relu output
    unsigned* binned = (unsigned*)alloc((size_t)nb * BCAP * 4);  // bucketed edges

    // ---- CSR build (fixed-capacity counting sort; no pre-histogram) ----
    hipMemsetAsync(bcursor, 0, NBMAX * sizeof(int), stream);
    k_bin<<<(E + BIN_CH - 1) / BIN_CH, 256, 0, stream>>>(src, dst, bcursor, binned,
                                                         hs, n, E);
    k_bfill<<<nb, 256, 0, stream>>>(binned, bcursor, rowptr, colidx, dinv, n);

    // ---- conv1 ----
    k_gemm_mfma<128, true><<<(n + 63) / 64, 256, 0, stream>>>(x, W1, dinv, hs, n);
    k_agg_relu<<<(n + 3) / 4, 256, 0, stream>>>(hs, rowptr, colidx, dinv, b1, bufA, n);

    // ---- conv2 + head ----
    k_gemm_mfma<64, false><<<(n + 63) / 64, 256, 0, stream>>>(bufA, W2, dinv, hs, n);
    k_agg_head<<<(n + 3) / 4, 256, 0, stream>>>(hs, rowptr, colidx, dinv, b2, Wl, bl,
                                                out, n);
}

// Round 3
// 148.665 us; speedup vs baseline: 1.2006x; 1.2006x over previous
//
#include <hip/hip_runtime.h>
#include <hip/hip_fp16.h>

// GCNRegressor: x[n,128] --GCNConv(W1)--> relu --GCNConv(W2)--> relu --@Wl+bl--> out[n]
// n=100000, E=1600000, IN=128, HID=64.
// R1: CSR-by-dst + gather aggregation (killed 102M fp32 atomics): 2913 -> 792 us.
// R2: 3-phase hierarchical scan + x4-unrolled gather: 792 -> 423 us.
// R3: two-level counting sort for CSR build (killed k_fill's 16x write amp): 423 -> 320.
// R4: fp16 scaled features (hs = h*dinv) halved the gather compulsory-fetch: 320 -> 302.
// R5: k_bin occupancy fix (BIN_CH 16384->2048) + deeper unroll: 302 -> 282.
// R6: 4-rows-per-VMEM gather (wave = 4 groups x 16 lanes): 282 -> 243.
// R7: register-tiled 4x4 fp32 GEMM (LDS-issue fix): 243 -> 225.
// R8: MFMA fp16 GEMMs + fp16 relu output + gather unroll 4: 225 -> 191.
// R9: fixed-capacity buckets (WIN) + gather unroll 8 (REGRESSION, VALU): 191 -> 178.
// R10: byte-offset colidx + packed rowptr (beg<<8|deg): 178 -> 171.
// R11: 8-rows-per-VMEM gather (wave = 8 groups x 8 lanes, uint4/lane): 41.8us agg.
// R12: dot2 + 2-slot loop: VALU cycles -19% but dur +3% -- serialized round-trips.
// R13: dot2 + branchy slot-skip: VALU cycles -25%, dur +15%. LESSON: the agg is
//      LATENCY-bound; VALUBusy was overlapped work hiding the 3-deep dependent
//      load chain. Branches between load-issue and consume poison the schedule.
// R14: 2 nodes per wave, software-pipelined: both nodes' rowptr, then all 8
//      colidx, then all 8 gather uint4s issued back-to-back (16 VMEM in
//      flight); node0 dots overlap node1's flight. Self-row/dinv hoisted to
//      wave start. Halves per-node exposed latency, zero extra traffic.
//      Epilogue computed once via lane-group split (group0->n0, group1->n1).

#define SHIFT 9
#define BSZ   (1 << SHIFT)     // 512 nodes per bucket
#define NBMAX 256
#define BIN_CH 2048
#define BCAP  12288            // per-bucket capacity (mean 8188, 1.5x slack)

using f16x8 = __attribute__((ext_vector_type(8))) _Float16;
using f16x2 = __attribute__((ext_vector_type(2))) _Float16;
using f32x4 = __attribute__((ext_vector_type(4))) float;

// ---- Phase 1: bin edges into fixed-capacity buckets; bcursor = counts ----
// pack src(17b) | local_node(9b)<<17. Block 0 also zeroes the dummy hs row.
__global__ __launch_bounds__(256) void k_bin(const int* __restrict__ src,
                                             const int* __restrict__ dst,
                                             int* __restrict__ bcursor,
                                             unsigned* __restrict__ binned,
                                             __half* __restrict__ hs, int n, int E) {
    if (blockIdx.x == 0 && threadIdx.x < 8) {
        uint4 z = {0u, 0u, 0u, 0u};
        reinterpret_cast<uint4*>(hs + ((size_t)n << 6))[threadIdx.x] = z;
    }
    __shared__ int h[NBMAX];
    __shared__ int base[NBMAX];
    const int beg = blockIdx.x * BIN_CH;
    const int end = min(beg + BIN_CH, E);
    for (int i = threadIdx.x; i < NBMAX; i += 256) h[i] = 0;
    __syncthreads();
    for (int e = beg + threadIdx.x; e < end; e += 256)
        atomicAdd(&h[dst[e] >> SHIFT], 1);
    __syncthreads();
    for (int i = threadIdx.x; i < NBMAX; i += 256) {
        base[i] = h[i] ? atomicAdd(&bcursor[i], h[i]) : 0;
        h[i] = 0;  // reuse as local cursor
    }
    __syncthreads();
    for (int e = beg + threadIdx.x; e < end; e += 256) {
        int d = dst[e];
        int b = d >> SHIFT;
        int off = atomicAdd(&h[b], 1);
        binned[(size_t)b * BCAP + base[b] + off] =
            (unsigned)src[e] | ((unsigned)(d & (BSZ - 1)) << 17);
    }
}

// ---- Phase 2: per-bucket prefix + LDS count + scan + packed rowptr + place ----
// rowptr[g] = (edge_base << 8) | deg ; colidx entry = src_row_byte_offset (src<<7)
__global__ __launch_bounds__(256) void k_bfill(const unsigned* __restrict__ binned,
                                               const int* __restrict__ counts,
                                               int* __restrict__ rowptr,
                                               int* __restrict__ colidx,
                                               float* __restrict__ dinv, int n) {
    __shared__ int cnt[BSZ];
    __shared__ int nbase[BSZ];
    __shared__ int stmp[256];
    const int b = blockIdx.x;
    const int t = threadIdx.x;
    // prefix sum of counts[0..b) -> ebeg (nb <= 256, single stride)
    stmp[t] = (t < b) ? counts[t] : 0;
    __syncthreads();
    for (int off = 128; off; off >>= 1) {
        if (t < off) stmp[t] += stmp[t + off];
        __syncthreads();
    }
    const int ebeg = stmp[0];
    const int ecnt = counts[b];
    __syncthreads();
    const unsigned* bp = binned + (size_t)b * BCAP;
    for (int i = t; i < BSZ; i += 256) cnt[i] = 0;
    __syncthreads();
    for (int e = t; e < ecnt; e += 256)
        atomicAdd(&cnt[bp[e] >> 17], 1);
    __syncthreads();
    int c0 = cnt[2 * t], c1 = cnt[2 * t + 1];
    int s = c0 + c1;
    stmp[t] = s;
    __syncthreads();
    for (int off = 1; off < 256; off <<= 1) {
        int u = (t >= off) ? stmp[t - off] : 0;
        __syncthreads();
        stmp[t] += u;
        __syncthreads();
    }
    int ex = stmp[t] - s;
    nbase[2 * t] = ex;
    nbase[2 * t + 1] = ex + c0;
    __syncthreads();
    const int gbase = b << SHIFT;
    for (int j = t; j < BSZ; j += 256) {
        int g = gbase + j;
        if (g < n) {
            rowptr[g] = (int)(((unsigned)(ebeg + nbase[j]) << 8) |
                              (unsigned)min(cnt[j], 255));
            dinv[g] = rsqrtf((float)cnt[j] + 1.0f);
        }
        cnt[j] = nbase[j];  // becomes local cursor
    }
    __syncthreads();
    for (int e = t; e < ecnt; e += 256) {
        unsigned p = bp[e];
        int j = p >> 17;
        int off = atomicAdd(&cnt[j], 1);
        colidx[ebeg + off] = (int)((p & 0x1FFFFu) << 7);  // byte offset of src row
    }
}

// MFMA GEMM: C16[n,64] = fp16( (A[n,K] @ W[K,64]) * dinv[row] ).
// Block = 256 threads = 4 waves; wave w computes rows rb+w*16..+15, all 64 cols.
template <int K, bool A_FP32>
__global__ __launch_bounds__(256) void k_gemm_mfma(const void* __restrict__ Av,
                                                   const float* __restrict__ W,
                                                   const float* __restrict__ dinv,
                                                   __half* __restrict__ C, int n) {
    constexpr int KP = K + 8;  // padded LDS row stride in halves (16B aligned)
    __shared__ _Float16 Wt[64 * KP];
    const int tid = threadIdx.x;
    for (int i = tid; i < K * 64; i += 256) {
        int k = i >> 6, c = i & 63;
        Wt[c * KP + k] = (_Float16)W[i];
    }
    __syncthreads();

    const int lane = tid & 63;
    const int wv = tid >> 6;
    const int r16 = lane & 15;
    const int kq = lane >> 4;                       // 0..3
    const int rb = blockIdx.x * 64 + wv * 16;
    const int arow = min(rb + r16, n - 1);          // clamped A row for this lane

    f32x4 acc[4] = {{0.f,0.f,0.f,0.f},{0.f,0.f,0.f,0.f},
                    {0.f,0.f,0.f,0.f},{0.f,0.f,0.f,0.f}};

#pragma unroll
    for (int kk = 0; kk < K; kk += 32) {
        f16x8 a;
        if (A_FP32) {
            const float* Ap = (const float*)Av + (size_t)arow * K + kk + kq * 8;
            float4 f0 = *reinterpret_cast<const float4*>(Ap);
            float4 f1 = *reinterpret_cast<const float4*>(Ap + 4);
            a[0] = (_Float16)f0.x; a[1] = (_Float16)f0.y;
            a[2] = (_Float16)f0.z; a[3] = (_Float16)f0.w;
            a[4] = (_Float16)f1.x; a[5] = (_Float16)f1.y;
            a[6] = (_Float16)f1.z; a[7] = (_Float16)f1.w;
        } else {
            const _Float16* Ap = (const _Float16*)Av + (size_t)arow * K + kk + kq * 8;
            a = *reinterpret_cast<const f16x8*>(Ap);
        }
#pragma unroll
        for (int nt = 0; nt < 4; ++nt) {
            f16x8 b = *reinterpret_cast<const f16x8*>(&Wt[(nt * 16 + r16) * KP + kk + kq * 8]);
            acc[nt] = __builtin_amdgcn_mfma_f32_16x16x32_f16(a, b, acc[nt], 0, 0, 0);
        }
    }

#pragma unroll
    for (int r = 0; r < 4; ++r) {
        const int row = rb + kq * 4 + r;
        if (row < n) {
            const float di = dinv[row];
#pragma unroll
            for (int nt = 0; nt < 4; ++nt)
                C[((size_t)row << 6) + nt * 16 + r16] = __float2half(acc[nt][r] * di);
        }
    }
}

// Accumulate 8 fp16 (one uint4) into acc[8] via v_dot2_f32_f16: one VALU op per
// value (convert+add fused, fp32 accumulate). Masks (1,0)/(0,1) keep channels
// separate; exact 1.0-multiply => bit-identical to cvt+add.
__device__ __forceinline__ void dotu4(float acc[8], uint4 u, f16x2 pl, f16x2 ph) {
    union { uint4 u4; f16x2 h[4]; } v;
    v.u4 = u;
    acc[0] = __builtin_amdgcn_fdot2(v.h[0], pl, acc[0], false);
    acc[1] = __builtin_amdgcn_fdot2(v.h[0], ph, acc[1], false);
    acc[2] = __builtin_amdgcn_fdot2(v.h[1], pl, acc[2], false);
    acc[3] = __builtin_amdgcn_fdot2(v.h[1], ph, acc[3], false);
    acc[4] = __builtin_amdgcn_fdot2(v.h[2], pl, acc[4], false);
    acc[5] = __builtin_amdgcn_fdot2(v.h[2], ph, acc[5], false);
    acc[6] = __builtin_amdgcn_fdot2(v.h[3], pl, acc[6], false);
    acc[7] = __builtin_amdgcn_fdot2(v.h[3], ph, acc[7], false);
}

// Fold partial sums across the 8 groups: after this every lane holds the full
// sums for its channel-slice p.
__device__ __forceinline__ void fold8(float acc[8]) {
#pragma unroll
    for (int m = 8; m <= 32; m <<= 1) {
#pragma unroll
        for (int j = 0; j < 8; ++j)
            acc[j] += __shfl_xor(acc[j], m, 64);
    }
}

// 2-node pipelined gather. Wave = 8 groups x 8 lanes; each group's uint4 load
// fetches one full 128B row. ALL loads for both nodes issued back-to-back
// (8 colidx dwords, then 8 gather uint4s = 16 VMEM in flight); node0's dot2s
// overlap node1's in-flight gathers. Unconditional 4 slots per node (deg<=32,
// ~all nodes; dummy-masked loads broadcast the hot zero row). Tail loops only
// for deg>32 (~1%), placed after the main dots (R11-proven shape).
__device__ __forceinline__ void gather_pair(const char* __restrict__ hsb,
                                            const int* __restrict__ colidx,
                                            unsigned pk0, unsigned pk1,
                                            int g, int p, unsigned dum,
                                            float acc0[8], float acc1[8]) {
    const f16x2 pl = {(_Float16)1.0f, (_Float16)0.0f};
    const f16x2 ph = {(_Float16)0.0f, (_Float16)1.0f};
    const int beg0 = (int)(pk0 >> 8), deg0 = (int)(pk0 & 255u);
    const int beg1 = (int)(pk1 >> 8), deg1 = (int)(pk1 & 255u);
    const int t0 = deg0 - g, t1 = deg1 - g;   // slot k valid iff 8*k < t
    const unsigned poff = (unsigned)(p << 4);
    const unsigned dumo = dum + poff;
    const int ia = beg0 + g;
    const int ib = beg1 + g;
    // --- issue all 8 colidx loads (slack past E is safe) ---
    unsigned a0 = (unsigned)colidx[ia]      + poff;
    unsigned a1 = (unsigned)colidx[ia + 8]  + poff;
    unsigned a2 = (unsigned)colidx[ia + 16] + poff;
    unsigned a3 = (unsigned)colidx[ia + 24] + poff;
    unsigned b0 = (unsigned)colidx[ib]      + poff;
    unsigned b1 = (unsigned)colidx[ib + 8]  + poff;
    unsigned b2 = (unsigned)colidx[ib + 16] + poff;
    unsigned b3 = (unsigned)colidx[ib + 24] + poff;
    unsigned oa0 = (0  < t0) ? a0 : dumo;
    unsigned oa1 = (8  < t0) ? a1 : dumo;
    unsigned oa2 = (16 < t0) ? a2 : dumo;
    unsigned oa3 = (24 < t0) ? a3 : dumo;
    unsigned ob0 = (0  < t1) ? b0 : dumo;
    unsigned ob1 = (8  < t1) ? b1 : dumo;
    unsigned ob2 = (16 < t1) ? b2 : dumo;
    unsigned ob3 = (24 < t1) ? b3 : dumo;
    // --- issue all 8 gathers ---
    uint4 ua0 = *reinterpret_cast<const uint4*>(hsb + oa0);
    uint4 ua1 = *reinterpret_cast<const uint4*>(hsb + oa1);
    uint4 ua2 = *reinterpret_cast<const uint4*>(hsb + oa2);
    uint4 ua3 = *reinterpret_cast<const uint4*>(hsb + oa3);
    uint4 ub0 = *reinterpret_cast<const uint4*>(hsb + ob0);
    uint4 ub1 = *reinterpret_cast<const uint4*>(hsb + ob1);
    uint4 ub2 = *reinterpret_cast<const uint4*>(hsb + ob2);
    uint4 ub3 = *reinterpret_cast<const uint4*>(hsb + ob3);
    // --- consume node0 while node1's gathers are still in flight ---
    dotu4(acc0, ua0, pl, ph);
    dotu4(acc0, ua1, pl, ph);
    dotu4(acc0, ua2, pl, ph);
    dotu4(acc0, ua3, pl, ph);
    dotu4(acc1, ub0, pl, ph);
    dotu4(acc1, ub1, pl, ph);
    dotu4(acc1, ub2, pl, ph);
    dotu4(acc1, ub3, pl, ph);
    // --- rare tails (deg > 32), wave-uniform, after the main dots ---
    const int ns0 = (deg0 + 7) >> 3;
    for (int k = 4; k < ns0; k += 4) {
        const int ik = beg0 + 8 * k + g;
        unsigned c0 = (unsigned)colidx[ik]      + poff;
        unsigned c1 = (unsigned)colidx[ik + 8]  + poff;
        unsigned c2 = (unsigned)colidx[ik + 16] + poff;
        unsigned c3 = (unsigned)colidx[ik + 24] + poff;
        const int kb = 8 * k;
        uint4 u0 = *reinterpret_cast<const uint4*>(hsb + ((kb      < t0) ? c0 : dumo));
        uint4 u1 = *reinterpret_cast<const uint4*>(hsb + ((kb + 8  < t0) ? c1 : dumo));
        uint4 u2 = *reinterpret_cast<const uint4*>(hsb + ((kb + 16 < t0) ? c2 : dumo));
        uint4 u3 = *reinterpret_cast<const uint4*>(hsb + ((kb + 24 < t0) ? c3 : dumo));
        dotu4(acc0, u0, pl, ph);
        dotu4(acc0, u1, pl, ph);
        dotu4(acc0, u2, pl, ph);
        dotu4(acc0, u3, pl, ph);
    }
    const int ns1 = (deg1 + 7) >> 3;
    for (int k = 4; k < ns1; k += 4) {
        const int ik = beg1 + 8 * k + g;
        unsigned c0 = (unsigned)colidx[ik]      + poff;
        unsigned c1 = (unsigned)colidx[ik + 8]  + poff;
        unsigned c2 = (unsigned)colidx[ik + 16] + poff;
        unsigned c3 = (unsigned)colidx[ik + 24] + poff;
        const int kb = 8 * k;
        uint4 u0 = *reinterpret_cast<const uint4*>(hsb + ((kb      < t1) ? c0 : dumo));
        uint4 u1 = *reinterpret_cast<const uint4*>(hsb + ((kb + 8  < t1) ? c1 : dumo));
        uint4 u2 = *reinterpret_cast<const uint4*>(hsb + ((kb + 16 < t1) ? c2 : dumo));
        uint4 u3 = *reinterpret_cast<const uint4*>(hsb + ((kb + 24 < t1) ? c3 : dumo));
        dotu4(acc1, u0, pl, ph);
        dotu4(acc1, u1, pl, ph);
        dotu4(acc1, u2, pl, ph);
        dotu4(acc1, u3, pl, ph);
    }
    fold8(acc0);
    fold8(acc1);
}

// conv1 aggregation: out16 = fp16(relu(di*(sum_e hs[src_e] + hs_i) + b)).
// 2 nodes per wave; epilogue once: lanes 0-7 -> node0, lanes 8-15 -> node1.
__global__ __launch_bounds__(256) void k_agg_relu(const __half* __restrict__ hs,
                                                  const int* __restrict__ rowptr,
                                                  const int* __restrict__ colidx,
                                                  const float* __restrict__ dinv,
                                                  const float* __restrict__ b,
                                                  __half* __restrict__ out, int n) {
    const int wv = threadIdx.x >> 6;
    const int i0 = blockIdx.x * 8 + wv * 2;
    const int lane = threadIdx.x & 63;
    if (i0 >= n) return;
    const int i1 = min(i0 + 1, n - 1);
    const int g = lane >> 3, p = lane & 7;
    // lane-group split: bit3 of lane selects which node this lane finalizes
    const int iw = (lane & 8) ? i1 : i0;
    // hoisted independent loads
    const unsigned pk0 = (unsigned)rowptr[i0];
    const unsigned pk1 = (unsigned)rowptr[i1];
    uint4 su = *reinterpret_cast<const uint4*>(hs + ((size_t)iw << 6) + (p << 3));
    const float di = dinv[iw];
    float acc0[8] = {}, acc1[8] = {};
    gather_pair((const char*)hs, colidx, pk0, pk1, g, p, (unsigned)n << 7,
                acc0, acc1);
    if (lane < 16) {
        const f16x2 pl = {(_Float16)1.0f, (_Float16)0.0f};
        const f16x2 ph = {(_Float16)0.0f, (_Float16)1.0f};
        float a[8];
#pragma unroll
        for (int j = 0; j < 8; ++j) a[j] = (lane & 8) ? acc1[j] : acc0[j];
        dotu4(a, su, pl, ph);
        float4 b0 = *reinterpret_cast<const float4*>(b + (p << 3));
        float4 b1 = *reinterpret_cast<const float4*>(b + (p << 3) + 4);
        __half2 h0 = __halves2half2(__float2half(fmaxf(fmaf(a[0], di, b0.x), 0.f)),
                                    __float2half(fmaxf(fmaf(a[1], di, b0.y), 0.f)));
        __half2 h1 = __halves2half2(__float2half(fmaxf(fmaf(a[2], di, b0.z), 0.f)),
                                    __float2half(fmaxf(fmaf(a[3], di, b0.w), 0.f)));
        __half2 h2 = __halves2half2(__float2half(fmaxf(fmaf(a[4], di, b1.x), 0.f)),
                                    __float2half(fmaxf(fmaf(a[5], di, b1.y), 0.f)));
        __half2 h3 = __halves2half2(__float2half(fmaxf(fmaf(a[6], di, b1.z), 0.f)),
                                    __float2half(fmaxf(fmaf(a[7], di, b1.w), 0.f)));
        uint4 u;
        u.x = *reinterpret_cast<unsigned*>(&h0);
        u.y = *reinterpret_cast<unsigned*>(&h1);
        u.z = *reinterpret_cast<unsigned*>(&h2);
        u.w = *reinterpret_cast<unsigned*>(&h3);
        if (iw < n && (i0 + 1 < n || !(lane & 8)))
            *reinterpret_cast<uint4*>(out + ((size_t)iw << 6) + (p << 3)) = u;
    }
}

// conv2 aggregation + relu + (.@Wl + bl) head, fused. 2 nodes per wave;
// even groups compute node0's products, odd groups node1's; xor-1,2,4 reduce
// stays within each 8-lane group -> lane0 holds v(node0), lane8 holds v(node1).
__global__ __launch_bounds__(256) void k_agg_head(const __half* __restrict__ hs,
                                                  const int* __restrict__ rowptr,
                                                  const int* __restrict__ colidx,
                                                  const float* __restrict__ dinv,
                                                  const float* __restrict__ b2,
                                                  const float* __restrict__ Wl,
                                                  const float* __restrict__ bl,
                                                  float* __restrict__ out, int n) {
    const int wv = threadIdx.x >> 6;
    const int i0 = blockIdx.x * 8 + wv * 2;
    const int lane = threadIdx.x & 63;
    if (i0 >= n) return;
    const int i1 = min(i0 + 1, n - 1);
    const int g = lane >> 3, p = lane & 7;
    const int iw = (lane & 8) ? i1 : i0;
    const unsigned pk0 = (unsigned)rowptr[i0];
    const unsigned pk1 = (unsigned)rowptr[i1];
    uint4 su = *reinterpret_cast<const uint4*>(hs + ((size_t)iw << 6) + (p << 3));
    const float di = dinv[iw];
    float acc0[8] = {}, acc1[8] = {};
    gather_pair((const char*)hs, colidx, pk0, pk1, g, p, (unsigned)n << 7,
                acc0, acc1);
    const f16x2 pl = {(_Float16)1.0f, (_Float16)0.0f};
    const f16x2 ph = {(_Float16)0.0f, (_Float16)1.0f};
    float a[8];
#pragma unroll
    for (int j = 0; j < 8; ++j) a[j] = (lane & 8) ? acc1[j] : acc0[j];
    dotu4(a, su, pl, ph);
    float4 b0 = *reinterpret_cast<const float4*>(b2 + (p << 3));
    float4 b1 = *reinterpret_cast<const float4*>(b2 + (p << 3) + 4);
    float4 w0 = *reinterpret_cast<const float4*>(Wl + (p << 3));
    float4 w1 = *reinterpret_cast<const float4*>(Wl + (p << 3) + 4);
    float v = fmaxf(fmaf(a[0], di, b0.x), 0.f) * w0.x
            + fmaxf(fmaf(a[1], di, b0.y), 0.f) * w0.y
            + fmaxf(fmaf(a[2], di, b0.z), 0.f) * w0.z
            + fmaxf(fmaf(a[3], di, b0.w), 0.f) * w0.w
            + fmaxf(fmaf(a[4], di, b1.x), 0.f) * w1.x
            + fmaxf(fmaf(a[5], di, b1.y), 0.f) * w1.y
            + fmaxf(fmaf(a[6], di, b1.z), 0.f) * w1.z
            + fmaxf(fmaf(a[7], di, b1.w), 0.f) * w1.w;
    v += __shfl_xor(v, 1, 64);
    v += __shfl_xor(v, 2, 64);
    v += __shfl_xor(v, 4, 64);
    if (lane == 0) out[i0] = v + bl[0];
    if (lane == 8 && i0 + 1 < n) out[i1] = v + bl[0];
}

extern "C" void kernel_launch(void* const* d_in, const int* in_sizes, int n_in,
                              void* d_out, int out_size, void* d_ws, size_t ws_size,
                              hipStream_t stream) {
    const float* x  = (const float*)d_in[0];
    const int*   ei = (const int*)d_in[1];
    const float* W1 = (const float*)d_in[2];
    const float* b1 = (const float*)d_in[3];
    const float* W2 = (const float*)d_in[4];
    const float* b2 = (const float*)d_in[5];
    const float* Wl = (const float*)d_in[6];
    const float* bl = (const float*)d_in[7];
    float* out = (float*)d_out;

    const int n = in_sizes[0] / 128;   // 100000
    const int E = in_sizes[1] / 2;     // 1600000
    const int* src = ei;
    const int* dst = ei + E;
    const int nb = (n + BSZ - 1) >> SHIFT;  // 196

    char* ws = (char*)d_ws;
    size_t o = 0;
    auto alloc = [&](size_t bytes) {
        void* p = ws + o;
        o = (o + bytes + 255) & ~(size_t)255;
        return p;
    };
    float* dinv    = (float*)alloc((size_t)n * 4);
    int*   bcursor = (int*)  alloc((size_t)NBMAX * 4);
    int*   rowptr  = (int*)  alloc((size_t)(n + 1) * 4);
    int*   colidx  = (int*)  alloc(((size_t)E + 64) * 4);        // +slack for unrolled reads
    __half* hs     = (__half*)alloc((size_t)(n + 1) * 64 * 2);   // +1 zeroed dummy row
    __half* bufA   = (__half*)alloc((size_t)n * 64 * 2);         // fp16 relu output
    unsigned* binned = (unsigned*)alloc((size_t)nb * BCAP * 4);  // bucketed edges

    // ---- CSR build (fixed-capacity counting sort; no pre-histogram) ----
    hipMemsetAsync(bcursor, 0, NBMAX * sizeof(int), stream);
    k_bin<<<(E + BIN_CH - 1) / BIN_CH, 256, 0, stream>>>(src, dst, bcursor, binned,
                                                         hs, n, E);
    k_bfill<<<nb, 256, 0, stream>>>(binned, bcursor, rowptr, colidx, dinv, n);

    // ---- conv1 ----
    k_gemm_mfma<128, true><<<(n + 63) / 64, 256, 0, stream>>>(x, W1, dinv, hs, n);
    k_agg_relu<<<(n + 7) / 8, 256, 0, stream>>>(hs, rowptr, colidx, dinv, b1, bufA, n);

    // ---- conv2 + head ----
    k_gemm_mfma<64, false><<<(n + 63) / 64, 256, 0, stream>>>(bufA, W2, dinv, hs, n);
    k_agg_head<<<(n + 7) / 8, 256, 0, stream>>>(hs, rowptr, colidx, dinv, b2, Wl, bl,
                                                out, n);
}